// Round 15
// baseline (264.581 us; speedup 1.0000x reference)
//
#include <hip/hip_runtime.h>
#include <cstdint>
#include <cstddef>

#define M_DIM 4096
#define K_DIM 4096
#define N_DIM 11008
#define BM 128
#define BN 256
#define BKB 64                        /* K bytes per step (one K=64 slice) */
#define NT (K_DIM / BKB)              /* 64 steps */
#define NTM (M_DIM / BM)              /* 32 */
#define NTN (N_DIM / BN)              /* 43 */
#define SLOT 24576                    /* A 8KB + B 16KB */
#define B_OFF 8192

typedef int   int4v   __attribute__((ext_vector_type(4)));
typedef float float4v __attribute__((ext_vector_type(4)));

__device__ __forceinline__ void gload_lds16(const void* g, void* l) {
  __builtin_amdgcn_global_load_lds(
      (const __attribute__((address_space(1))) unsigned int*)g,
      (__attribute__((address_space(3))) unsigned int*)l, 16, 0, 0);
}

// ---------------- x quantization: fp32 -> int8 ----------------
__global__ void quant_x_kernel(const float* __restrict__ x,
                               const float* __restrict__ scale_p,
                               const int* __restrict__ off_p,
                               signed char* __restrict__ xq, int total16) {
  const float inv = 1.0f / scale_p[0];
  const float off = (float)off_p[0];
  int tid = blockIdx.x * blockDim.x + threadIdx.x;
  int stride = gridDim.x * blockDim.x;
  const float4v* x4 = (const float4v*)x;
  int4v* out4 = (int4v*)xq;
  for (int i = tid; i < total16; i += stride) {
    int4v o;
#pragma unroll
    for (int j = 0; j < 4; ++j) {
      float4v v = x4[(size_t)i * 4 + j];
      int r = 0;
#pragma unroll
      for (int e = 0; e < 4; ++e) {
        float q = rintf(v[e] * inv) + off;     // round-half-even, matches jnp.round
        q = fminf(fmaxf(q, -128.0f), 127.0f);
        int qi = (int)q;
        r |= (qi & 0xff) << (8 * e);
      }
      o[j] = r;
    }
    out4[i] = o;
  }
}

// ---------------- weight pack: int32 carrier -> int8 ----------------
__global__ void pack_w_kernel(const int* __restrict__ w,
                              signed char* __restrict__ wq, int total16) {
  int tid = blockIdx.x * blockDim.x + threadIdx.x;
  int stride = gridDim.x * blockDim.x;
  const int4v* w4 = (const int4v*)w;
  int4v* out4 = (int4v*)wq;
  for (int i = tid; i < total16; i += stride) {
    int4v o;
#pragma unroll
    for (int j = 0; j < 4; ++j) {
      int4v v = w4[(size_t)i * 4 + j];
      o[j] = (v[0] & 0xff) | ((v[1] & 0xff) << 8) |
             ((v[2] & 0xff) << 16) | ((v[3] & 0xff) << 24);
    }
    out4[i] = o;
  }
}

// ---- int8 GEMM: 128x256, 4 waves x (64x128), ring-3, 2 blocks/CU,      ----
// ---- full-step register read-ahead with RACE-FREE publication (R15).   ----
// A: xq [M][K] int8, B: wq [N][K] int8 (B^T), out fp32 [M][N]
// LDS swizzle (R12-verified, 0 conflicts): 64-B rows, physical chunk p of
// row r holds logical chunk p ^ ((r>>1)&3); DMA dest linear, source
// pre-swizzled.
// Step t: {STG(t+2)->c2; RD(tile t+1 -> alternate regs) from c1 [slot
// confirmed by PREVIOUS barrier: its DMA was vmcnt(0)-drained before that
// barrier]; 32 MFMA on current regs (no dep on RD -> port drains under the
// matrix pipe); lgkm(0); vmcnt(0) [own 6 loads aged ~full step]; barrier}.
// R14's bug: it read a slot whose DMA was drained only by the *reader's own*
// vmcnt, never published by a barrier -> cross-wave race.  Here every read
// target was drained by ALL waves before the barrier that precedes the read.
__global__ __launch_bounds__(256, 2) void gemm_i8_kernel(
    const signed char* __restrict__ A,
    const signed char* __restrict__ B,
    const int* __restrict__ qbias,
    const float* __restrict__ dscale,
    float* __restrict__ out) {
  __shared__ __attribute__((aligned(16))) signed char lds[3 * SLOT];  // 72 KB

  const int tid  = threadIdx.x;
  const int lane = tid & 63;
  const int wv   = tid >> 6;   // 0..3
  const int wr   = wv >> 1;    // 0..1  (M half: 64 rows)
  const int wc   = wv & 1;     // 0..1  (N half: 128 cols)

  // XCD swizzle: 1376 blocks, 172/XCD; xcd owns tm {4x..4x+3}; 4 adjacent
  // blocks share one 1MB B panel (L2).
  int bid = blockIdx.x;
  int s   = bid >> 3;                  // 0..171
  int tm  = 4 * (bid & 7) + (s & 3);   // 0..31
  int tn  = s >> 2;                    // 0..42

  // ---- staging (pre-swizzled source, linear dest; R12-verified) ----
  const int csw = (((lane & 3) ^ ((lane >> 3) & 3)) << 4);
  const signed char* sA0 = A + (size_t)(tm * BM + wv * 16 + (lane >> 2)) * K_DIM + csw;
  const signed char* sB0 = B + (size_t)(tn * BN + wv * 64 + (lane >> 2)) * K_DIM + csw;
  const int dA0 = wv * 1024 + lane * 16;                 // frag wv   (+4096: frag wv+4)
  const int dB0 = B_OFF + wv * 4096 + lane * 16;         // frags wv*4 + j

#define STG(KT, SO) do {                                                      \
    gload_lds16(sA0 + (size_t)(KT) * BKB,                    lds + (SO) + dA0);        \
    gload_lds16(sA0 + (size_t)64 * K_DIM + (size_t)(KT) * BKB, lds + (SO) + dA0 + 4096); \
    _Pragma("unroll") for (int j = 0; j < 4; ++j)                             \
      gload_lds16(sB0 + (size_t)j * 16 * K_DIM + (size_t)(KT) * BKB,          \
                  lds + (SO) + dB0 + j * 1024);                               \
  } while (0)

  // ---- ds_read constants (R12-verified conflict-free) ----
  const int rp  = ((((lane >> 4) ^ (lane >> 1)) & 3) << 4);
  const int rdA = (wr * 4) * 1024 + (lane & 15) * 64 + rp;          // + m*1024
  const int rdB = B_OFF + (wc * 8) * 1024 + (lane & 15) * 64 + rp;  // + n*1024

#define RD(AF, BF, SB) do {                                                   \
    _Pragma("unroll") for (int m = 0; m < 4; ++m)                             \
      AF[m] = *(const int4v*)(lds + (SB) + rdA + m * 1024);                   \
    _Pragma("unroll") for (int n = 0; n < 8; ++n)                             \
      BF[n] = *(const int4v*)(lds + (SB) + rdB + n * 1024); } while (0)

#define MM(AF, BF) do {                                                       \
    __builtin_amdgcn_s_setprio(1);                                            \
    _Pragma("unroll") for (int m = 0; m < 4; ++m)                             \
      _Pragma("unroll") for (int n = 0; n < 8; ++n)                           \
        acc[m][n] = __builtin_amdgcn_mfma_i32_16x16x64_i8(                    \
            AF[m], BF[n], acc[m][n], 0, 0, 0);                                \
    __builtin_amdgcn_s_setprio(0); } while (0)

  // Step: STG(t+2)->c2; RD(next regs)<-c1 (confirmed by last barrier);
  // MFMA current; lgkm(0); vmcnt(0); barrier; rotate.
#define STEP(KT2, CUR_A, CUR_B, NXT_A, NXT_B) do {                            \
    STG((KT2) & (NT - 1), c2);                                                \
    RD(NXT_A, NXT_B, c1);                                                     \
    MM(CUR_A, CUR_B);                                                         \
    asm volatile("s_waitcnt lgkmcnt(0)" ::: "memory");                        \
    __builtin_amdgcn_sched_barrier(0);                                        \
    asm volatile("s_waitcnt vmcnt(0)" ::: "memory");                          \
    __builtin_amdgcn_s_barrier();                                             \
    int _r = c0; c0 = c1; c1 = c2; c2 = _r;                                   \
  } while (0)

  int4v acc[4][8];
#pragma unroll
  for (int i = 0; i < 4; ++i)
#pragma unroll
    for (int j = 0; j < 8; ++j) acc[i][j] = (int4v){0, 0, 0, 0};

  int4v afrE[4], bfrE[8], afrO[4], bfrO[8];
  int c0 = 0, c1 = SLOT, c2 = 2 * SLOT;

  // ---- prologue: stage tiles 0,1; confirm BOTH; read tile-0 operands ----
  STG(0, 0);
  STG(1, SLOT);
  asm volatile("s_waitcnt vmcnt(0)" ::: "memory");   // slots 0,1 landed
  __builtin_amdgcn_s_barrier();                      // published to all waves
  RD(afrE, bfrE, 0);
  asm volatile("s_waitcnt lgkmcnt(0)" ::: "memory"); // tile-0 regs ready
  __builtin_amdgcn_sched_barrier(0);

  for (int t = 0; t < NT; t += 2) {
    STEP(t + 2, afrE, bfrE, afrO, bfrO);   // compute tile t,   read t+1
    STEP(t + 3, afrO, bfrO, afrE, bfrE);   // compute tile t+1, read t+2
  }
#undef STEP
#undef MM
#undef RD
#undef STG

  // ---- epilogue: out[m][n] = (acc + qbias[n]) * dscale[n] ----
  const int col = lane & 15;
  const int rb  = (lane >> 4) * 4;
  const int gm0 = tm * BM + wr * 64;
  const int gn0 = tn * BN + wc * 128;
#pragma unroll
  for (int n = 0; n < 8; ++n) {
    int gn = gn0 + n * 16 + col;
    float ds = dscale[gn];
    int qb = qbias[gn];
#pragma unroll
    for (int m = 0; m < 4; ++m) {
      int gm = gm0 + m * 16 + rb;
#pragma unroll
      for (int j = 0; j < 4; ++j)
        out[(size_t)(gm + j) * N_DIM + gn] = (float)(acc[m][n][j] + qb) * ds;
    }
  }
}

extern "C" void kernel_launch(void* const* d_in, const int* in_sizes, int n_in,
                              void* d_out, int out_size, void* d_ws, size_t ws_size,
                              hipStream_t stream) {
  const float* x      = (const float*)d_in[0];
  const int*   w      = (const int*)d_in[1];
  const float* dscale = (const float*)d_in[2];
  const float* iscale = (const float*)d_in[3];
  const int*   ioff   = (const int*)d_in[4];
  const int*   qbias  = (const int*)d_in[5];
  float* out = (float*)d_out;

  const size_t xq_bytes = (size_t)M_DIM * K_DIM;        // 16 MB
  const size_t wq_bytes = (size_t)N_DIM * K_DIM;        // 45 MB
  if (ws_size < xq_bytes + wq_bytes) return;

  signed char* xq = (signed char*)d_ws;
  signed char* wq = (signed char*)d_ws + xq_bytes;

  quant_x_kernel<<<2048, 256, 0, stream>>>(x, iscale, ioff, xq, M_DIM * K_DIM / 16);
  pack_w_kernel<<<2048, 256, 0, stream>>>(w, wq, N_DIM * K_DIM / 16);
  gemm_i8_kernel<<<NTM * NTN, 256, 0, stream>>>(xq, wq, qbias, dscale, out);
}

// Round 16
// 258.097 us; speedup vs baseline: 1.0251x; 1.0251x over previous
//
#include <hip/hip_runtime.h>
#include <cstdint>
#include <cstddef>

#define M_DIM 4096
#define K_DIM 4096
#define N_DIM 11008
#define BM 128
#define BN 256
#define BKB 64                        /* K bytes per step (one K=64 slice) */
#define NT (K_DIM / BKB)              /* 64 steps */
#define NTM (M_DIM / BM)              /* 32 */
#define NTN (N_DIM / BN)              /* 43 */
#define SLOT 24576                    /* A 8KB + B 16KB */
#define B_OFF 8192

typedef int   int4v   __attribute__((ext_vector_type(4)));
typedef float float4v __attribute__((ext_vector_type(4)));

__device__ __forceinline__ void gload_lds16(const void* g, void* l) {
  __builtin_amdgcn_global_load_lds(
      (const __attribute__((address_space(1))) unsigned int*)g,
      (__attribute__((address_space(3))) unsigned int*)l, 16, 0, 0);
}

// ---------------- x quantization: fp32 -> int8 ----------------
__global__ void quant_x_kernel(const float* __restrict__ x,
                               const float* __restrict__ scale_p,
                               const int* __restrict__ off_p,
                               signed char* __restrict__ xq, int total16) {
  const float inv = 1.0f / scale_p[0];
  const float off = (float)off_p[0];
  int tid = blockIdx.x * blockDim.x + threadIdx.x;
  int stride = gridDim.x * blockDim.x;
  const float4v* x4 = (const float4v*)x;
  int4v* out4 = (int4v*)xq;
  for (int i = tid; i < total16; i += stride) {
    int4v o;
#pragma unroll
    for (int j = 0; j < 4; ++j) {
      float4v v = x4[(size_t)i * 4 + j];
      int r = 0;
#pragma unroll
      for (int e = 0; e < 4; ++e) {
        float q = rintf(v[e] * inv) + off;     // round-half-even, matches jnp.round
        q = fminf(fmaxf(q, -128.0f), 127.0f);
        int qi = (int)q;
        r |= (qi & 0xff) << (8 * e);
      }
      o[j] = r;
    }
    out4[i] = o;
  }
}

// ---------------- weight pack: int32 carrier -> int8 ----------------
__global__ void pack_w_kernel(const int* __restrict__ w,
                              signed char* __restrict__ wq, int total16) {
  int tid = blockIdx.x * blockDim.x + threadIdx.x;
  int stride = gridDim.x * blockDim.x;
  const int4v* w4 = (const int4v*)w;
  int4v* out4 = (int4v*)wq;
  for (int i = tid; i < total16; i += stride) {
    int4v o;
#pragma unroll
    for (int j = 0; j < 4; ++j) {
      int4v v = w4[(size_t)i * 4 + j];
      o[j] = (v[0] & 0xff) | ((v[1] & 0xff) << 8) |
             ((v[2] & 0xff) << 16) | ((v[3] & 0xff) << 24);
    }
    out4[i] = o;
  }
}

// ---- int8 GEMM: 128x256, 4 waves x (64x128), ring-3, 2 blocks/CU (R12   ----
// ---- schedule) with LOOP-INVARIANT ADDRESSING (unroll-3, base+imm).     ----
// A: xq [M][K] int8, B: wq [N][K] int8 (B^T), out fp32 [M][N]
// LDS swizzle (R12-verified, 0 conflicts): 64-B rows, physical chunk p of
// row r holds logical chunk p ^ ((r>>1)&3); DMA dest linear, source
// pre-swizzled.  Step t (slot = t%3, compile-time via unroll-3):
// {12 ds_reads in consumption order (A0-3,B0,B1 then B2-7) as base+imm;
//  STG(t+2) via 6 invariant pointers (+imm per unrolled step);
//  4 MFMA groups with counted lgkm(6/4/2/0);
//  vmcnt(6) [drains STG(t+1), aged 1 full step] ; s_barrier}.
__global__ __launch_bounds__(256, 2) void gemm_i8_kernel(
    const signed char* __restrict__ A,
    const signed char* __restrict__ B,
    const int* __restrict__ qbias,
    const float* __restrict__ dscale,
    float* __restrict__ out) {
  __shared__ __attribute__((aligned(16))) signed char lds[3 * SLOT];  // 72 KB

  const int tid  = threadIdx.x;
  const int lane = tid & 63;
  const int wv   = tid >> 6;   // 0..3
  const int wr   = wv >> 1;    // 0..1  (M half: 64 rows)
  const int wc   = wv & 1;     // 0..1  (N half: 128 cols)

  // XCD swizzle: 1376 blocks, 172/XCD; xcd owns tm {4x..4x+3}; 4 adjacent
  // blocks share one 1MB B panel (L2).
  int bid = blockIdx.x;
  int s   = bid >> 3;                  // 0..171
  int tm  = 4 * (bid & 7) + (s & 3);   // 0..31
  int tn  = s >> 2;                    // 0..42

  // ---- staging (pre-swizzled source, linear dest; R12-verified) ----
  const int csw = (((lane & 3) ^ ((lane >> 3) & 3)) << 4);
  const signed char* sA0 = A + (size_t)(tm * BM + wv * 16 + (lane >> 2)) * K_DIM + csw;
  const signed char* sB0 = B + (size_t)(tn * BN + wv * 64 + (lane >> 2)) * K_DIM + csw;
  const int dA0 = wv * 1024 + lane * 16;                 // frag wv   (+4096: frag wv+4)
  const int dB0 = B_OFF + wv * 4096 + lane * 16;         // frags wv*4 + j

  // 6 invariant staging bases + fixed LDS dest offsets
  const signed char* gp0 = sA0;
  const signed char* gp1 = sA0 + (size_t)64 * K_DIM;
  const signed char* gp2 = sB0;
  const signed char* gp3 = sB0 + (size_t)16 * K_DIM;
  const signed char* gp4 = sB0 + (size_t)32 * K_DIM;
  const signed char* gp5 = sB0 + (size_t)48 * K_DIM;

#define STG(KT, SO) do {                                                      \
    gload_lds16(gp0 + (size_t)(KT) * BKB, lds + (SO) + dA0);                  \
    gload_lds16(gp1 + (size_t)(KT) * BKB, lds + (SO) + dA0 + 4096);           \
    gload_lds16(gp2 + (size_t)(KT) * BKB, lds + (SO) + dB0);                  \
    gload_lds16(gp3 + (size_t)(KT) * BKB, lds + (SO) + dB0 + 1024);           \
    gload_lds16(gp4 + (size_t)(KT) * BKB, lds + (SO) + dB0 + 2048);           \
    gload_lds16(gp5 + (size_t)(KT) * BKB, lds + (SO) + dB0 + 3072);           \
  } while (0)

  // ---- ds_read invariant bases (R12-verified conflict-free swizzle) ----
  const int rp  = ((((lane >> 4) ^ (lane >> 1)) & 3) << 4);
  const signed char* pA = lds + (wr * 4) * 1024 + (lane & 15) * 64 + rp;
  const signed char* pB = lds + B_OFF + (wc * 8) * 1024 + (lane & 15) * 64 + rp;

#define RA(S, m) (*(const int4v*)(pA + (S) + (m) * 1024))
#define RB(S, n) (*(const int4v*)(pB + (S) + (n) * 1024))

#define LG(n) do {                                                            \
    asm volatile("s_waitcnt lgkmcnt(" #n ")" ::: "memory");                   \
    __builtin_amdgcn_sched_barrier(0); } while (0)
#define MMG2(N0) do {                                                         \
    __builtin_amdgcn_s_setprio(1);                                            \
    _Pragma("unroll") for (int nn = 0; nn < 2; ++nn)                          \
      _Pragma("unroll") for (int m = 0; m < 4; ++m)                           \
        acc[m][(N0) + nn] = __builtin_amdgcn_mfma_i32_16x16x64_i8(            \
            afr[m], bfr[(N0) + nn], acc[m][(N0) + nn], 0, 0, 0);              \
    __builtin_amdgcn_s_setprio(0); } while (0)

  // STEP: S = compile-time slot of tile t; S2 = slot of t+2.  MODE: 0 normal,
  // 1 = no stage + vmcnt(0) (step 62), 2 = no stage/no wait (step 63).
#define STEP(KT2, S, S2, MODE) do {                                           \
    afr[0] = RA(S, 0); afr[1] = RA(S, 1); afr[2] = RA(S, 2); afr[3] = RA(S, 3); \
    bfr[0] = RB(S, 0); bfr[1] = RB(S, 1);                                     \
    if ((MODE) == 0) STG((KT2), (S2));                                        \
    bfr[2] = RB(S, 2); bfr[3] = RB(S, 3); bfr[4] = RB(S, 4);                  \
    bfr[5] = RB(S, 5); bfr[6] = RB(S, 6); bfr[7] = RB(S, 7);                  \
    LG(6); MMG2(0);                                                           \
    LG(4); MMG2(2);                                                           \
    LG(2); MMG2(4);                                                           \
    LG(0); MMG2(6);                                                           \
    if ((MODE) == 0)      asm volatile("s_waitcnt vmcnt(6)" ::: "memory");    \
    else if ((MODE) == 1) asm volatile("s_waitcnt vmcnt(0)" ::: "memory");    \
    if ((MODE) != 2) __builtin_amdgcn_s_barrier();                            \
  } while (0)

  int4v acc[4][8];
#pragma unroll
  for (int i = 0; i < 4; ++i)
#pragma unroll
    for (int j = 0; j < 8; ++j) acc[i][j] = (int4v){0, 0, 0, 0};

  int4v afr[4], bfr[8];

  // ---- prologue: stage steps 0,1; slot0 drained (vmcnt 12->6); publish ----
  STG(0, 0);
  STG(1, SLOT);
  asm volatile("s_waitcnt vmcnt(6)" ::: "memory");
  __builtin_amdgcn_s_barrier();

  // main: 20 iters x 3 steps (t = 0..59), slots compile-time {0,1,2}
  for (int t3 = 0; t3 < 60; t3 += 3) {
    STEP(t3 + 2, 0,        2 * SLOT, 0);
    STEP(t3 + 3, SLOT,     0,        0);
    STEP(t3 + 4, 2 * SLOT, SLOT,     0);
  }
  // tail: steps 60..63 (slots 0,1,2,0)
  STEP(62, 0,        2 * SLOT, 0);   // step 60
  STEP(63, SLOT,     0,        0);   // step 61
  STEP(0,  2 * SLOT, 0,        1);   // step 62: no stage, vmcnt(0)
  STEP(0,  0,        0,        2);   // step 63: no stage, no wait
#undef STEP
#undef MMG2
#undef LG
#undef RB
#undef RA
#undef STG

  // ---- epilogue: out[m][n] = (acc + qbias[n]) * dscale[n] ----
  const int col = lane & 15;
  const int rb  = (lane >> 4) * 4;
  const int gm0 = tm * BM + wr * 64;
  const int gn0 = tn * BN + wc * 128;
#pragma unroll
  for (int n = 0; n < 8; ++n) {
    int gn = gn0 + n * 16 + col;
    float ds = dscale[gn];
    int qb = qbias[gn];
#pragma unroll
    for (int m = 0; m < 4; ++m) {
      int gm = gm0 + m * 16 + rb;
#pragma unroll
      for (int j = 0; j < 4; ++j)
        out[(size_t)(gm + j) * N_DIM + gn] = (float)(acc[m][n][j] + qb) * ds;
    }
  }
}

extern "C" void kernel_launch(void* const* d_in, const int* in_sizes, int n_in,
                              void* d_out, int out_size, void* d_ws, size_t ws_size,
                              hipStream_t stream) {
  const float* x      = (const float*)d_in[0];
  const int*   w      = (const int*)d_in[1];
  const float* dscale = (const float*)d_in[2];
  const float* iscale = (const float*)d_in[3];
  const int*   ioff   = (const int*)d_in[4];
  const int*   qbias  = (const int*)d_in[5];
  float* out = (float*)d_out;

  const size_t xq_bytes = (size_t)M_DIM * K_DIM;        // 16 MB
  const size_t wq_bytes = (size_t)N_DIM * K_DIM;        // 45 MB
  if (ws_size < xq_bytes + wq_bytes) return;

  signed char* xq = (signed char*)d_ws;
  signed char* wq = (signed char*)d_ws + xq_bytes;

  quant_x_kernel<<<2048, 256, 0, stream>>>(x, iscale, ioff, xq, M_DIM * K_DIM / 16);
  pack_w_kernel<<<2048, 256, 0, stream>>>(w, wq, N_DIM * K_DIM / 16);
  gemm_i8_kernel<<<NTM * NTN, 256, 0, stream>>>(xq, wq, qbias, dscale, out);
}